// Round 1
// 1023.711 us; speedup vs baseline: 1.1190x; 1.1190x over previous
//
#include <hip/hip_runtime.h>

// Linear SSM group scan: chunk-4 parallel phases + 2-level inter-chunk scan.
// G=2, B=128, L=2048, SD=64, ID=16, OD=16. All fp32, exact decomposition.
//
// R1 rewrite of kA/kC: wave-per-component-range mapping.
//   block = (g, half, c4): 64 items (lane = item = batch index), 4 waves,
//   wave ww computes state components [16ww,16ww+16) for all 64 items.
//   State is regathered via LDS zb[comp][item] (no global round-trip,
//   no vmcnt(0) serialization). 4-way split accumulators for ILP.
//   kA writes ONLY zend4 (slot l0+3) - intermediate slots never consumed.
// kB0/kB1/kB2 unchanged from previous session.
#define G_ 2
#define B_ 128
#define L_ 2048
#define SD 64
#define ID 16
#define OD 16
#define NC4 512
#define NC8 256
#define OBS_BASE ((size_t)(G_) * B_ * L_ * SD)

typedef float v2 __attribute__((ext_vector_type(2)));

static __device__ __forceinline__ size_t slotof(int g, int b, int l) {
  return (((size_t)g * B_ + b) * L_ + l) * (size_t)SD;
}
static __device__ __forceinline__ float rl(float v, int lane) {
  return __builtin_bit_cast(float, __builtin_amdgcn_readlane(__builtin_bit_cast(int, v), lane));
}

// C = A*A (64x64), 256 threads. Caller syncs before and after.
static __device__ void lds_sq(const float* A, float* C, int tid) {
  const int r = tid & 63, q = tid >> 6;
  const float4* Ar = (const float4*)(A + r * SD);
  float acc[16];
#pragma unroll
  for (int c = 0; c < 16; ++c) acc[c] = 0.f;
#pragma unroll 1
  for (int k4 = 0; k4 < 16; ++k4) {
    float4 af = Ar[k4];
    const float* Bb = A + k4 * 4 * SD + q * 16;
#pragma unroll
    for (int kk = 0; kk < 4; ++kk) {
      float a = (kk == 0) ? af.x : (kk == 1) ? af.y : (kk == 2) ? af.z : af.w;
      const float4* Bk = (const float4*)(Bb + kk * SD);
#pragma unroll
      for (int c = 0; c < 4; ++c) {
        float4 bv = Bk[c];
        acc[4 * c + 0] = fmaf(a, bv.x, acc[4 * c + 0]);
        acc[4 * c + 1] = fmaf(a, bv.y, acc[4 * c + 1]);
        acc[4 * c + 2] = fmaf(a, bv.z, acc[4 * c + 2]);
        acc[4 * c + 3] = fmaf(a, bv.w, acc[4 * c + 3]);
      }
    }
  }
  float4* Cr = (float4*)(C + r * SD + q * 16);
#pragma unroll
  for (int c = 0; c < 4; ++c)
    Cr[c] = make_float4(acc[4 * c], acc[4 * c + 1], acc[4 * c + 2], acc[4 * c + 3]);
}

// ---------------------------------------------------------------------------
// kA: zero-init chunk-4 recurrence (fused noise coloring + input drive).
// Writes ONLY zend4 = slot l0+3 (the value the kB chain consumes).
// Grid 2048: bid -> (g = bid>>10, half = (bid>>9)&1, c4 = bid&511).
// ---------------------------------------------------------------------------
__global__ __launch_bounds__(256, 2) void kA(
    const float* __restrict__ wn, const float* __restrict__ inp,
    const float* __restrict__ Fm, const float* __restrict__ Bm,
    const float* __restrict__ SW, float* __restrict__ out) {
  __shared__ __align__(16) float Fl[SD * SD];   // 16 KB
  __shared__ __align__(16) float Wl[SD * SD];   // 16 KB
  __shared__ __align__(16) float Bl[SD * ID];   // 4 KB
  __shared__ __align__(16) float zb[SD * 64];   // 16 KB [comp][item]
  const int tid = threadIdx.x;
  const int bid = (int)blockIdx.x;
  const int c4 = bid & (NC4 - 1);
  const int half = (bid >> 9) & 1;
  const int g = bid >> 10;
  const int l0 = c4 * 4;
  {
    const float4* Fg = (const float4*)(Fm + g * SD * SD);
    const float4* Wg = (const float4*)(SW + g * SD * SD);
    float4* F4 = (float4*)Fl;
    float4* W4 = (float4*)Wl;
    for (int i = tid; i < SD * SD / 4; i += 256) { F4[i] = Fg[i]; W4[i] = Wg[i]; }
    const float4* Bg = (const float4*)(Bm + g * SD * ID);
    ((float4*)Bl)[tid & 255] = Bg[tid & 255];  // 256 float4 = blockDim
  }
  const int lane = tid & 63;
  const int ww = tid >> 6;
  const int b = half * 64 + lane;
  const int row0 = ww * 16;

  v2 z2[32];
#pragma unroll
  for (int k = 0; k < 32; ++k) z2[k] = (v2){0.f, 0.f};

#pragma unroll 1
  for (int j = 0; j < 4; ++j) {
    const int l = l0 + j;
    float4 w4[16];
    const float4* wp = (const float4*)(wn + (((size_t)l * G_ + g) * B_ + b) * SD);
#pragma unroll
    for (int q = 0; q < 16; ++q) w4[q] = wp[q];
    float4 u4[4];
    const float4* up = (const float4*)(inp + (((size_t)g * B_ + b) * L_ + l) * ID);
#pragma unroll
    for (int q = 0; q < 4; ++q) u4[q] = up[q];
    __syncthreads();  // A: mats ready (j==0); prev-step zb reads drained (j>0)
#pragma unroll 1
    for (int c = 0; c < 16; ++c) {
      const int row = row0 + c;
      const float4* fr = (const float4*)(Fl + row * SD);
      const float4* sr = (const float4*)(Wl + row * SD);
      const float4* br = (const float4*)(Bl + row * ID);
      v2 a0 = {0.f, 0.f}, a1 = {0.f, 0.f}, a2 = {0.f, 0.f}, a3 = {0.f, 0.f};
#pragma unroll
      for (int q = 0; q < 16; ++q) {
        float4 f = fr[q];
        float4 s = sr[q];
        float4 w = w4[q];
        a0 += (v2){f.x, f.y} * z2[2 * q];
        a1 += (v2){f.z, f.w} * z2[2 * q + 1];
        a2 += (v2){s.x, s.y} * (v2){w.x, w.y};
        a3 += (v2){s.z, s.w} * (v2){w.z, w.w};
      }
#pragma unroll
      for (int q = 0; q < 4; ++q) {
        float4 bb = br[q];
        float4 u = u4[q];
        a2 += (v2){bb.x, bb.y} * (v2){u.x, u.y};
        a3 += (v2){bb.z, bb.w} * (v2){u.z, u.w};
      }
      v2 aa = (a0 + a1) + (a2 + a3);
      zb[row * 64 + lane] = aa.x + aa.y;
    }
    __syncthreads();  // B: zb complete
    if (j != 3) {
#pragma unroll
      for (int k = 0; k < 32; ++k)
        z2[k] = (v2){zb[(2 * k) * 64 + lane], zb[(2 * k + 1) * 64 + lane]};
    }
  }
  // cooperative zend4 store: thread (item, kg) -> comps [16kg,16kg+16)
  {
    const int item = tid & 63;
    const int kg = tid >> 6;
    float* dst = out + slotof(g, half * 64 + item, l0 + 3);
#pragma unroll
    for (int r = 0; r < 4; ++r) {
      float4 v;
      v.x = zb[(kg * 16 + 4 * r + 0) * 64 + item];
      v.y = zb[(kg * 16 + 4 * r + 1) * 64 + item];
      v.z = zb[(kg * 16 + 4 * r + 2) * 64 + item];
      v.w = zb[(kg * 16 + 4 * r + 3) * 64 + item];
      ((float4*)dst)[kg * 4 + r] = v;
    }
  }
}

// ---------------------------------------------------------------------------
// kB0: d(c8) = F^4 * zend4(2c8) + zend4(2c8+1)  -> slot c8*8+0   (unchanged)
// ---------------------------------------------------------------------------
__global__ __launch_bounds__(256) void kB0(const float* __restrict__ Fm,
                                           float* __restrict__ out) {
  __shared__ __align__(16) float bufA[SD * SD];
  __shared__ __align__(16) float bufB[SD * SD];
  const int tid = threadIdx.x;
  const int idx = (int)blockIdx.x * 256 + tid;
  const int b = idx & 127;
  const int rest = idx >> 7;
  const int c8 = rest & (NC8 - 1);
  const int g = rest >> 8;
  {
    const float4* Fg = (const float4*)(Fm + g * SD * SD);
    float4* A4 = (float4*)bufA;
    for (int i = tid; i < SD * SD / 4; i += 256) A4[i] = Fg[i];
  }
  __syncthreads();
  lds_sq(bufA, bufB, tid);  __syncthreads();  // F^2
  lds_sq(bufB, bufA, tid);  __syncthreads();  // F^4 in bufA

  const float* za_p = out + slotof(g, b, c8 * 8 + 3);
  const float* zb_p = out + slotof(g, b, c8 * 8 + 7);
  float* d_p = out + slotof(g, b, c8 * 8);
  v2 x2[32];
  {
    const float4* xp = (const float4*)za_p;
#pragma unroll
    for (int q = 0; q < 16; ++q) {
      float4 f = xp[q];
      x2[2 * q] = (v2){f.x, f.y};
      x2[2 * q + 1] = (v2){f.z, f.w};
    }
  }
#pragma unroll 1
  for (int tg = 0; tg < 16; ++tg) {
    float4 zb4 = ((const float4*)zb_p)[tg];
    float zn[4];
#pragma unroll
    for (int i = 0; i < 4; ++i) {
      const float4* fr = (const float4*)(bufA + (tg * 4 + i) * SD);
      v2 acc = {0.f, 0.f};
#pragma unroll
      for (int q = 0; q < 16; ++q) {
        float4 f = fr[q];
        acc += (v2){f.x, f.y} * x2[2 * q] + (v2){f.z, f.w} * x2[2 * q + 1];
      }
      zn[i] = acc.x + acc.y + ((i == 0) ? zb4.x : (i == 1) ? zb4.y : (i == 2) ? zb4.z : zb4.w);
    }
    ((float4*)d_p)[tg] = make_float4(zn[0], zn[1], zn[2], zn[3]);
  }
}

// ---------------------------------------------------------------------------
// kB1: sequential chunk-8 scan. init8(c8+1) = F^8*init8(c8) + d(c8). (unchanged)
// ---------------------------------------------------------------------------
__global__ __launch_bounds__(256) void kB1(const float* __restrict__ Fm,
                                           const float* __restrict__ s0,
                                           float* __restrict__ out) {
  __shared__ __align__(16) float bufA[SD * SD];
  __shared__ __align__(16) float bufB[SD * SD];
  const int tid = threadIdx.x;
  const int gb = (int)blockIdx.x * 4 + (tid >> 6);
  const int g = gb >> 7, b = gb & 127;
  const int lane = tid & 63;
  {
    const int gg = ((int)blockIdx.x * 4) >> 7;  // uniform per block
    const float4* Fg = (const float4*)(Fm + gg * SD * SD);
    float4* A4 = (float4*)bufA;
    for (int i = tid; i < SD * SD / 4; i += 256) A4[i] = Fg[i];
  }
  __syncthreads();
  lds_sq(bufA, bufB, tid);  __syncthreads();  // F^2
  lds_sq(bufB, bufA, tid);  __syncthreads();  // F^4
  lds_sq(bufA, bufB, tid);  __syncthreads();  // F^8 in bufB

  float frow[SD];
  const float4* Fr = (const float4*)(bufB + lane * SD);
#pragma unroll
  for (int i = 0; i < 16; ++i) {
    float4 f = Fr[i];
    frow[4 * i] = f.x; frow[4 * i + 1] = f.y; frow[4 * i + 2] = f.z; frow[4 * i + 3] = f.w;
  }
  float s = s0[(g * B_ + b) * SD + lane];
  float dcur = out[slotof(g, b, 0) + lane];
  float dnext = out[slotof(g, b, 8) + lane];
#pragma unroll 1
  for (int c8 = 0; c8 < NC8; ++c8) {
    asm volatile("s_waitcnt vmcnt(0)" ::: "memory");  // dcur/dnext/dpf resident
    out[slotof(g, b, c8 * 8) + lane] = s;             // init8(c8); d(c8) already in regs
    const int cn = (c8 + 2 < NC8) ? c8 + 2 : NC8 - 1;
    float dpf = out[slotof(g, b, cn * 8) + lane];
    float a0 = dcur, a1 = 0.f, a2 = 0.f, a3 = 0.f;
#pragma unroll
    for (int k = 0; k < SD; k += 4) {
      a0 = fmaf(frow[k + 0], rl(s, k + 0), a0);
      a1 = fmaf(frow[k + 1], rl(s, k + 1), a1);
      a2 = fmaf(frow[k + 2], rl(s, k + 2), a2);
      a3 = fmaf(frow[k + 3], rl(s, k + 3), a3);
    }
    s = (a0 + a1) + (a2 + a3);
    dcur = dnext;
    dnext = dpf;
  }
}

// ---------------------------------------------------------------------------
// kB2: odd chunk-4 inits: init4(2c8+1) = F^4*init8(c8) + zend4(2c8). (unchanged)
// ---------------------------------------------------------------------------
__global__ __launch_bounds__(256) void kB2(const float* __restrict__ Fm,
                                           float* __restrict__ out) {
  __shared__ __align__(16) float bufA[SD * SD];
  __shared__ __align__(16) float bufB[SD * SD];
  const int tid = threadIdx.x;
  const int idx = (int)blockIdx.x * 256 + tid;
  const int b = idx & 127;
  const int rest = idx >> 7;
  const int c8 = rest & (NC8 - 1);
  const int g = rest >> 8;
  {
    const float4* Fg = (const float4*)(Fm + g * SD * SD);
    float4* A4 = (float4*)bufA;
    for (int i = tid; i < SD * SD / 4; i += 256) A4[i] = Fg[i];
  }
  __syncthreads();
  lds_sq(bufA, bufB, tid);  __syncthreads();
  lds_sq(bufB, bufA, tid);  __syncthreads();  // F^4 in bufA

  const float* x_p = out + slotof(g, b, c8 * 8);       // init8(c8)
  const float* zb_p = out + slotof(g, b, c8 * 8 + 3);  // zend4(2c8)
  float* o_p = out + slotof(g, b, c8 * 8 + 4);
  v2 x2[32];
  {
    const float4* xp = (const float4*)x_p;
#pragma unroll
    for (int q = 0; q < 16; ++q) {
      float4 f = xp[q];
      x2[2 * q] = (v2){f.x, f.y};
      x2[2 * q + 1] = (v2){f.z, f.w};
    }
  }
#pragma unroll 1
  for (int tg = 0; tg < 16; ++tg) {
    float4 zb4 = ((const float4*)zb_p)[tg];
    float zn[4];
#pragma unroll
    for (int i = 0; i < 4; ++i) {
      const float4* fr = (const float4*)(bufA + (tg * 4 + i) * SD);
      v2 acc = {0.f, 0.f};
#pragma unroll
      for (int q = 0; q < 16; ++q) {
        float4 f = fr[q];
        acc += (v2){f.x, f.y} * x2[2 * q] + (v2){f.z, f.w} * x2[2 * q + 1];
      }
      zn[i] = acc.x + acc.y + ((i == 0) ? zb4.x : (i == 1) ? zb4.y : (i == 2) ? zb4.z : zb4.w);
    }
    ((float4*)o_p)[tg] = make_float4(zn[0], zn[1], zn[2], zn[3]);
  }
}

// ---------------------------------------------------------------------------
// kC: true chunk-4 recurrence from init (slot l0), wave-per-component-range.
// State regathered through zb; per-step cooperative state store + fused obs.
// ---------------------------------------------------------------------------
__global__ __launch_bounds__(256, 2) void kC(
    const float* __restrict__ wn, const float* __restrict__ inp,
    const float* __restrict__ vn, const float* __restrict__ Fm,
    const float* __restrict__ Bm, const float* __restrict__ Hm,
    const float* __restrict__ SW, const float* __restrict__ SV,
    float* __restrict__ out) {
  __shared__ __align__(16) float Fl[SD * SD];   // 16 KB
  __shared__ __align__(16) float Wl[SD * SD];   // 16 KB
  __shared__ __align__(16) float Bl[SD * ID];   // 4 KB
  __shared__ __align__(16) float Hl[OD * SD];   // 4 KB
  __shared__ __align__(16) float Vl[OD * OD];   // 1 KB
  __shared__ __align__(16) float zb[SD * 64];   // 16 KB [comp][item]
  __shared__ __align__(16) float ob[OD * 64];   // 4 KB  [oc][item]
  const int tid = threadIdx.x;
  const int bid = (int)blockIdx.x;
  const int c4 = bid & (NC4 - 1);
  const int half = (bid >> 9) & 1;
  const int g = bid >> 10;
  const int l0 = c4 * 4;
  {
    const float4* Fg = (const float4*)(Fm + g * SD * SD);
    const float4* Wg = (const float4*)(SW + g * SD * SD);
    float4* F4 = (float4*)Fl;
    float4* W4 = (float4*)Wl;
    for (int i = tid; i < SD * SD / 4; i += 256) { F4[i] = Fg[i]; W4[i] = Wg[i]; }
    const float4* Bg = (const float4*)(Bm + g * SD * ID);
    ((float4*)Bl)[tid & 255] = Bg[tid & 255];
    const float4* Hg = (const float4*)(Hm + g * OD * SD);
    ((float4*)Hl)[tid & 255] = Hg[tid & 255];
    if (tid < OD * OD / 4) ((float4*)Vl)[tid] = ((const float4*)(SV + g * OD * OD))[tid];
  }
  const int lane = tid & 63;
  const int ww = tid >> 6;
  const int b = half * 64 + lane;
  const int row0 = ww * 16;
  const int item = tid & 63;   // cooperative-store role
  const int kg = tid >> 6;

  v2 z2[32];
  {
    // init4(c4): per-lane contiguous load from slot l0 (written by kB1/kB2)
    const float4* ip = (const float4*)(out + slotof(g, b, l0));
#pragma unroll
    for (int q = 0; q < 16; ++q) {
      float4 f = ip[q];
      z2[2 * q] = (v2){f.x, f.y};
      z2[2 * q + 1] = (v2){f.z, f.w};
    }
  }
#pragma unroll 1
  for (int j = 0; j < 4; ++j) {
    const int l = l0 + j;
    float4 w4[16];
    const float4* wp = (const float4*)(wn + (((size_t)l * G_ + g) * B_ + b) * SD);
#pragma unroll
    for (int q = 0; q < 16; ++q) w4[q] = wp[q];
    float4 u4[4];
    const float4* up = (const float4*)(inp + (((size_t)g * B_ + b) * L_ + l) * ID);
#pragma unroll
    for (int q = 0; q < 4; ++q) u4[q] = up[q];
    float4 v4[4];
    const float4* vp = (const float4*)(vn + (((size_t)l * G_ + g) * B_ + b) * OD);
#pragma unroll
    for (int q = 0; q < 4; ++q) v4[q] = vp[q];

    __syncthreads();  // A: mats ready (j==0); prev-step zb/ob readers drained
#pragma unroll 1
    for (int c = 0; c < 16; ++c) {
      const int row = row0 + c;
      const float4* fr = (const float4*)(Fl + row * SD);
      const float4* sr = (const float4*)(Wl + row * SD);
      const float4* br = (const float4*)(Bl + row * ID);
      v2 a0 = {0.f, 0.f}, a1 = {0.f, 0.f}, a2 = {0.f, 0.f}, a3 = {0.f, 0.f};
#pragma unroll
      for (int q = 0; q < 16; ++q) {
        float4 f = fr[q];
        float4 s = sr[q];
        float4 w = w4[q];
        a0 += (v2){f.x, f.y} * z2[2 * q];
        a1 += (v2){f.z, f.w} * z2[2 * q + 1];
        a2 += (v2){s.x, s.y} * (v2){w.x, w.y};
        a3 += (v2){s.z, s.w} * (v2){w.z, w.w};
      }
#pragma unroll
      for (int q = 0; q < 4; ++q) {
        float4 bb = br[q];
        float4 u = u4[q];
        a2 += (v2){bb.x, bb.y} * (v2){u.x, u.y};
        a3 += (v2){bb.z, bb.w} * (v2){u.z, u.w};
      }
      v2 aa = (a0 + a1) + (a2 + a3);
      zb[row * 64 + lane] = aa.x + aa.y;
    }
    __syncthreads();  // B: zb = state(l) complete
    // cooperative state store
    {
      float* dst = out + slotof(g, half * 64 + item, l);
#pragma unroll
      for (int r = 0; r < 4; ++r) {
        float4 v;
        v.x = zb[(kg * 16 + 4 * r + 0) * 64 + item];
        v.y = zb[(kg * 16 + 4 * r + 1) * 64 + item];
        v.z = zb[(kg * 16 + 4 * r + 2) * 64 + item];
        v.w = zb[(kg * 16 + 4 * r + 3) * 64 + item];
        ((float4*)dst)[kg * 4 + r] = v;
      }
    }
    // regather full state(l) into regs (also feeds next step)
#pragma unroll
    for (int k = 0; k < 32; ++k)
      z2[k] = (v2){zb[(2 * k) * 64 + lane], zb[(2 * k + 1) * 64 + lane]};
    // observations: wave ww computes obs rows [4ww, 4ww+4)
#pragma unroll
    for (int oc = 0; oc < 4; ++oc) {
      const int orow = ww * 4 + oc;
      const float4* hr = (const float4*)(Hl + orow * SD);
      const float4* vr = (const float4*)(Vl + orow * OD);
      v2 a0 = {0.f, 0.f}, a1 = {0.f, 0.f};
#pragma unroll
      for (int q = 0; q < 16; ++q) {
        float4 h = hr[q];
        a0 += (v2){h.x, h.y} * z2[2 * q];
        a1 += (v2){h.z, h.w} * z2[2 * q + 1];
      }
#pragma unroll
      for (int q = 0; q < 4; ++q) {
        float4 sv = vr[q];
        float4 vv = v4[q];
        a0 += (v2){sv.x, sv.y} * (v2){vv.x, vv.y};
        a1 += (v2){sv.z, sv.w} * (v2){vv.z, vv.w};
      }
      v2 aa = a0 + a1;
      ob[orow * 64 + lane] = aa.x + aa.y;
    }
    __syncthreads();  // C: ob complete
    // cooperative obs store: thread (item, kg) stores float4 #kg
    {
      float4 v;
      v.x = ob[(4 * kg + 0) * 64 + item];
      v.y = ob[(4 * kg + 1) * 64 + item];
      v.z = ob[(4 * kg + 2) * 64 + item];
      v.w = ob[(4 * kg + 3) * 64 + item];
      float* od = out + OBS_BASE +
                  (((size_t)g * B_ + (half * 64 + item)) * L_ + l) * OD;
      ((float4*)od)[kg] = v;
    }
  }
}

extern "C" void kernel_launch(void* const* d_in, const int* in_sizes, int n_in,
                              void* d_out, int out_size, void* d_ws, size_t ws_size,
                              hipStream_t stream) {
  (void)in_sizes; (void)n_in; (void)out_size; (void)d_ws; (void)ws_size;
  const float* state0 = (const float*)d_in[0];
  const float* inputs = (const float*)d_in[1];
  const float* Fm     = (const float*)d_in[2];
  const float* Bm     = (const float*)d_in[3];
  const float* Hm     = (const float*)d_in[4];
  const float* SW     = (const float*)d_in[5];
  const float* SV     = (const float*)d_in[6];
  const float* wn     = (const float*)d_in[7];
  const float* vn     = (const float*)d_in[8];
  float* out = (float*)d_out;

  kA<<<2048, 256, 0, stream>>>(wn, inputs, Fm, Bm, SW, out);
  kB0<<<256, 256, 0, stream>>>(Fm, out);
  kB1<<<64, 256, 0, stream>>>(Fm, state0, out);
  kB2<<<256, 256, 0, stream>>>(Fm, out);
  kC<<<2048, 256, 0, stream>>>(wn, inputs, vn, Fm, Bm, Hm, SW, SV, out);
}

// Round 2
// 986.877 us; speedup vs baseline: 1.1608x; 1.0373x over previous
//
#include <hip/hip_runtime.h>

// Linear SSM group scan: chunk-4 parallel phases + 2-level inter-chunk scan.
// G=2, B=128, L=2048, SD=64, ID=16, OD=16. All fp32, exact decomposition.
//
// R2: kA/kC matrices moved from LDS-broadcast reads to the SCALAR path.
//   All matrix indices are wave-uniform (ww readfirstlane'd), so hipcc
//   scalarizes the loads to s_load_dwordx4 (K$-cached). This removes the
//   576 broadcast ds_read_b128 per wave-step that were the R1 bottleneck
//   (12 cyc each for 16 B unique data = 369 us floor, matching measurement).
//   LDS keeps only zb/ob state exchange + cooperative stores.
// kB0/kB1/kB2 unchanged.
#define G_ 2
#define B_ 128
#define L_ 2048
#define SD 64
#define ID 16
#define OD 16
#define NC4 512
#define NC8 256
#define OBS_BASE ((size_t)(G_) * B_ * L_ * SD)

typedef float v2 __attribute__((ext_vector_type(2)));

static __device__ __forceinline__ size_t slotof(int g, int b, int l) {
  return (((size_t)g * B_ + b) * L_ + l) * (size_t)SD;
}
static __device__ __forceinline__ float rl(float v, int lane) {
  return __builtin_bit_cast(float, __builtin_amdgcn_readlane(__builtin_bit_cast(int, v), lane));
}

// C = A*A (64x64), 256 threads. Caller syncs before and after.
static __device__ void lds_sq(const float* A, float* C, int tid) {
  const int r = tid & 63, q = tid >> 6;
  const float4* Ar = (const float4*)(A + r * SD);
  float acc[16];
#pragma unroll
  for (int c = 0; c < 16; ++c) acc[c] = 0.f;
#pragma unroll 1
  for (int k4 = 0; k4 < 16; ++k4) {
    float4 af = Ar[k4];
    const float* Bb = A + k4 * 4 * SD + q * 16;
#pragma unroll
    for (int kk = 0; kk < 4; ++kk) {
      float a = (kk == 0) ? af.x : (kk == 1) ? af.y : (kk == 2) ? af.z : af.w;
      const float4* Bk = (const float4*)(Bb + kk * SD);
#pragma unroll
      for (int c = 0; c < 4; ++c) {
        float4 bv = Bk[c];
        acc[4 * c + 0] = fmaf(a, bv.x, acc[4 * c + 0]);
        acc[4 * c + 1] = fmaf(a, bv.y, acc[4 * c + 1]);
        acc[4 * c + 2] = fmaf(a, bv.z, acc[4 * c + 2]);
        acc[4 * c + 3] = fmaf(a, bv.w, acc[4 * c + 3]);
      }
    }
  }
  float4* Cr = (float4*)(C + r * SD + q * 16);
#pragma unroll
  for (int c = 0; c < 4; ++c)
    Cr[c] = make_float4(acc[4 * c], acc[4 * c + 1], acc[4 * c + 2], acc[4 * c + 3]);
}

// ---------------------------------------------------------------------------
// kA: zero-init chunk-4 recurrence (fused noise coloring + input drive).
// Writes ONLY zend4 = slot l0+3. Matrices read via scalar path (uniform idx).
// Grid 2048: bid -> (g = bid>>10, half = (bid>>9)&1, c4 = bid&511).
// ---------------------------------------------------------------------------
__global__ __launch_bounds__(256, 2) void kA(
    const float* __restrict__ wn, const float* __restrict__ inp,
    const float* __restrict__ Fm, const float* __restrict__ Bm,
    const float* __restrict__ SW, float* __restrict__ out) {
  __shared__ __align__(16) float zb[SD * 64];   // 16 KB [comp][item]
  const int tid = threadIdx.x;
  const int bid = (int)blockIdx.x;
  const int c4 = bid & (NC4 - 1);
  const int half = (bid >> 9) & 1;
  const int g = bid >> 10;               // uniform (blockIdx)
  const int l0 = c4 * 4;
  const int lane = tid & 63;
  const int ww = __builtin_amdgcn_readfirstlane(tid >> 6);  // uniform wave id
  const int b = half * 64 + lane;
  const int row0 = ww * 16;              // uniform
  const float* __restrict__ Fg = Fm + g * SD * SD;
  const float* __restrict__ Wg = SW + g * SD * SD;
  const float* __restrict__ Bg = Bm + g * SD * ID;

  v2 z2[32];
#pragma unroll
  for (int k = 0; k < 32; ++k) z2[k] = (v2){0.f, 0.f};

#pragma unroll 1
  for (int j = 0; j < 4; ++j) {
    const int l = l0 + j;
    float4 w4[16];
    const float4* wp = (const float4*)(wn + (((size_t)l * G_ + g) * B_ + b) * SD);
#pragma unroll
    for (int q = 0; q < 16; ++q) w4[q] = wp[q];
    float4 u4[4];
    const float4* up = (const float4*)(inp + (((size_t)g * B_ + b) * L_ + l) * ID);
#pragma unroll
    for (int q = 0; q < 4; ++q) u4[q] = up[q];
    __syncthreads();  // A: prev-step zb reads drained (no-op at j==0)
#pragma unroll 1
    for (int c = 0; c < 16; ++c) {
      const int row = row0 + c;  // uniform
      const float4* fr = (const float4*)(Fg + row * SD);
      const float4* sr = (const float4*)(Wg + row * SD);
      const float4* br = (const float4*)(Bg + row * ID);
      v2 a0 = {0.f, 0.f}, a1 = {0.f, 0.f}, a2 = {0.f, 0.f}, a3 = {0.f, 0.f};
#pragma unroll
      for (int q = 0; q < 16; ++q) {
        float4 f = fr[q];   // uniform -> s_load
        float4 s = sr[q];   // uniform -> s_load
        float4 w = w4[q];
        a0 += (v2){f.x, f.y} * z2[2 * q];
        a1 += (v2){f.z, f.w} * z2[2 * q + 1];
        a2 += (v2){s.x, s.y} * (v2){w.x, w.y};
        a3 += (v2){s.z, s.w} * (v2){w.z, w.w};
      }
#pragma unroll
      for (int q = 0; q < 4; ++q) {
        float4 bb = br[q];  // uniform -> s_load
        float4 u = u4[q];
        a2 += (v2){bb.x, bb.y} * (v2){u.x, u.y};
        a3 += (v2){bb.z, bb.w} * (v2){u.z, u.w};
      }
      v2 aa = (a0 + a1) + (a2 + a3);
      zb[row * 64 + lane] = aa.x + aa.y;
    }
    __syncthreads();  // B: zb complete
    if (j != 3) {
#pragma unroll
      for (int k = 0; k < 32; ++k)
        z2[k] = (v2){zb[(2 * k) * 64 + lane], zb[(2 * k + 1) * 64 + lane]};
    }
  }
  // cooperative zend4 store: thread (item, kg) -> comps [16kg,16kg+16)
  {
    const int item = tid & 63;
    const int kg = tid >> 6;
    float* dst = out + slotof(g, half * 64 + item, l0 + 3);
#pragma unroll
    for (int r = 0; r < 4; ++r) {
      float4 v;
      v.x = zb[(kg * 16 + 4 * r + 0) * 64 + item];
      v.y = zb[(kg * 16 + 4 * r + 1) * 64 + item];
      v.z = zb[(kg * 16 + 4 * r + 2) * 64 + item];
      v.w = zb[(kg * 16 + 4 * r + 3) * 64 + item];
      ((float4*)dst)[kg * 4 + r] = v;
    }
  }
}

// ---------------------------------------------------------------------------
// kB0: d(c8) = F^4 * zend4(2c8) + zend4(2c8+1)  -> slot c8*8+0   (unchanged)
// ---------------------------------------------------------------------------
__global__ __launch_bounds__(256) void kB0(const float* __restrict__ Fm,
                                           float* __restrict__ out) {
  __shared__ __align__(16) float bufA[SD * SD];
  __shared__ __align__(16) float bufB[SD * SD];
  const int tid = threadIdx.x;
  const int idx = (int)blockIdx.x * 256 + tid;
  const int b = idx & 127;
  const int rest = idx >> 7;
  const int c8 = rest & (NC8 - 1);
  const int g = rest >> 8;
  {
    const float4* Fg = (const float4*)(Fm + g * SD * SD);
    float4* A4 = (float4*)bufA;
    for (int i = tid; i < SD * SD / 4; i += 256) A4[i] = Fg[i];
  }
  __syncthreads();
  lds_sq(bufA, bufB, tid);  __syncthreads();  // F^2
  lds_sq(bufB, bufA, tid);  __syncthreads();  // F^4 in bufA

  const float* za_p = out + slotof(g, b, c8 * 8 + 3);
  const float* zb_p = out + slotof(g, b, c8 * 8 + 7);
  float* d_p = out + slotof(g, b, c8 * 8);
  v2 x2[32];
  {
    const float4* xp = (const float4*)za_p;
#pragma unroll
    for (int q = 0; q < 16; ++q) {
      float4 f = xp[q];
      x2[2 * q] = (v2){f.x, f.y};
      x2[2 * q + 1] = (v2){f.z, f.w};
    }
  }
#pragma unroll 1
  for (int tg = 0; tg < 16; ++tg) {
    float4 zb4 = ((const float4*)zb_p)[tg];
    float zn[4];
#pragma unroll
    for (int i = 0; i < 4; ++i) {
      const float4* fr = (const float4*)(bufA + (tg * 4 + i) * SD);
      v2 acc = {0.f, 0.f};
#pragma unroll
      for (int q = 0; q < 16; ++q) {
        float4 f = fr[q];
        acc += (v2){f.x, f.y} * x2[2 * q] + (v2){f.z, f.w} * x2[2 * q + 1];
      }
      zn[i] = acc.x + acc.y + ((i == 0) ? zb4.x : (i == 1) ? zb4.y : (i == 2) ? zb4.z : zb4.w);
    }
    ((float4*)d_p)[tg] = make_float4(zn[0], zn[1], zn[2], zn[3]);
  }
}

// ---------------------------------------------------------------------------
// kB1: sequential chunk-8 scan. init8(c8+1) = F^8*init8(c8) + d(c8). (unchanged)
// ---------------------------------------------------------------------------
__global__ __launch_bounds__(256) void kB1(const float* __restrict__ Fm,
                                           const float* __restrict__ s0,
                                           float* __restrict__ out) {
  __shared__ __align__(16) float bufA[SD * SD];
  __shared__ __align__(16) float bufB[SD * SD];
  const int tid = threadIdx.x;
  const int gb = (int)blockIdx.x * 4 + (tid >> 6);
  const int g = gb >> 7, b = gb & 127;
  const int lane = tid & 63;
  {
    const int gg = ((int)blockIdx.x * 4) >> 7;  // uniform per block
    const float4* Fg = (const float4*)(Fm + gg * SD * SD);
    float4* A4 = (float4*)bufA;
    for (int i = tid; i < SD * SD / 4; i += 256) A4[i] = Fg[i];
  }
  __syncthreads();
  lds_sq(bufA, bufB, tid);  __syncthreads();  // F^2
  lds_sq(bufB, bufA, tid);  __syncthreads();  // F^4
  lds_sq(bufA, bufB, tid);  __syncthreads();  // F^8 in bufB

  float frow[SD];
  const float4* Fr = (const float4*)(bufB + lane * SD);
#pragma unroll
  for (int i = 0; i < 16; ++i) {
    float4 f = Fr[i];
    frow[4 * i] = f.x; frow[4 * i + 1] = f.y; frow[4 * i + 2] = f.z; frow[4 * i + 3] = f.w;
  }
  float s = s0[(g * B_ + b) * SD + lane];
  float dcur = out[slotof(g, b, 0) + lane];
  float dnext = out[slotof(g, b, 8) + lane];
#pragma unroll 1
  for (int c8 = 0; c8 < NC8; ++c8) {
    asm volatile("s_waitcnt vmcnt(0)" ::: "memory");  // dcur/dnext/dpf resident
    out[slotof(g, b, c8 * 8) + lane] = s;             // init8(c8); d(c8) already in regs
    const int cn = (c8 + 2 < NC8) ? c8 + 2 : NC8 - 1;
    float dpf = out[slotof(g, b, cn * 8) + lane];
    float a0 = dcur, a1 = 0.f, a2 = 0.f, a3 = 0.f;
#pragma unroll
    for (int k = 0; k < SD; k += 4) {
      a0 = fmaf(frow[k + 0], rl(s, k + 0), a0);
      a1 = fmaf(frow[k + 1], rl(s, k + 1), a1);
      a2 = fmaf(frow[k + 2], rl(s, k + 2), a2);
      a3 = fmaf(frow[k + 3], rl(s, k + 3), a3);
    }
    s = (a0 + a1) + (a2 + a3);
    dcur = dnext;
    dnext = dpf;
  }
}

// ---------------------------------------------------------------------------
// kB2: odd chunk-4 inits: init4(2c8+1) = F^4*init8(c8) + zend4(2c8). (unchanged)
// ---------------------------------------------------------------------------
__global__ __launch_bounds__(256) void kB2(const float* __restrict__ Fm,
                                           float* __restrict__ out) {
  __shared__ __align__(16) float bufA[SD * SD];
  __shared__ __align__(16) float bufB[SD * SD];
  const int tid = threadIdx.x;
  const int idx = (int)blockIdx.x * 256 + tid;
  const int b = idx & 127;
  const int rest = idx >> 7;
  const int c8 = rest & (NC8 - 1);
  const int g = rest >> 8;
  {
    const float4* Fg = (const float4*)(Fm + g * SD * SD);
    float4* A4 = (float4*)bufA;
    for (int i = tid; i < SD * SD / 4; i += 256) A4[i] = Fg[i];
  }
  __syncthreads();
  lds_sq(bufA, bufB, tid);  __syncthreads();
  lds_sq(bufB, bufA, tid);  __syncthreads();  // F^4 in bufA

  const float* x_p = out + slotof(g, b, c8 * 8);       // init8(c8)
  const float* zb_p = out + slotof(g, b, c8 * 8 + 3);  // zend4(2c8)
  float* o_p = out + slotof(g, b, c8 * 8 + 4);
  v2 x2[32];
  {
    const float4* xp = (const float4*)x_p;
#pragma unroll
    for (int q = 0; q < 16; ++q) {
      float4 f = xp[q];
      x2[2 * q] = (v2){f.x, f.y};
      x2[2 * q + 1] = (v2){f.z, f.w};
    }
  }
#pragma unroll 1
  for (int tg = 0; tg < 16; ++tg) {
    float4 zb4 = ((const float4*)zb_p)[tg];
    float zn[4];
#pragma unroll
    for (int i = 0; i < 4; ++i) {
      const float4* fr = (const float4*)(bufA + (tg * 4 + i) * SD);
      v2 acc = {0.f, 0.f};
#pragma unroll
      for (int q = 0; q < 16; ++q) {
        float4 f = fr[q];
        acc += (v2){f.x, f.y} * x2[2 * q] + (v2){f.z, f.w} * x2[2 * q + 1];
      }
      zn[i] = acc.x + acc.y + ((i == 0) ? zb4.x : (i == 1) ? zb4.y : (i == 2) ? zb4.z : zb4.w);
    }
    ((float4*)o_p)[tg] = make_float4(zn[0], zn[1], zn[2], zn[3]);
  }
}

// ---------------------------------------------------------------------------
// kC: true chunk-4 recurrence from init (slot l0), wave-per-component-range,
// matrices via scalar path; state regathered through zb; fused obs.
// ---------------------------------------------------------------------------
__global__ __launch_bounds__(256, 2) void kC(
    const float* __restrict__ wn, const float* __restrict__ inp,
    const float* __restrict__ vn, const float* __restrict__ Fm,
    const float* __restrict__ Bm, const float* __restrict__ Hm,
    const float* __restrict__ SW, const float* __restrict__ SV,
    float* __restrict__ out) {
  __shared__ __align__(16) float zb[SD * 64];   // 16 KB [comp][item]
  __shared__ __align__(16) float ob[OD * 64];   // 4 KB  [oc][item]
  const int tid = threadIdx.x;
  const int bid = (int)blockIdx.x;
  const int c4 = bid & (NC4 - 1);
  const int half = (bid >> 9) & 1;
  const int g = bid >> 10;               // uniform
  const int l0 = c4 * 4;
  const int lane = tid & 63;
  const int ww = __builtin_amdgcn_readfirstlane(tid >> 6);  // uniform wave id
  const int b = half * 64 + lane;
  const int row0 = ww * 16;              // uniform
  const int item = tid & 63;             // cooperative-store role
  const int kg = tid >> 6;
  const float* __restrict__ Fg = Fm + g * SD * SD;
  const float* __restrict__ Wg = SW + g * SD * SD;
  const float* __restrict__ Bg = Bm + g * SD * ID;
  const float* __restrict__ Hg = Hm + g * OD * SD;
  const float* __restrict__ Vg = SV + g * OD * OD;

  v2 z2[32];
  {
    // init4(c4): per-lane contiguous load from slot l0 (written by kB1/kB2)
    const float4* ip = (const float4*)(out + slotof(g, b, l0));
#pragma unroll
    for (int q = 0; q < 16; ++q) {
      float4 f = ip[q];
      z2[2 * q] = (v2){f.x, f.y};
      z2[2 * q + 1] = (v2){f.z, f.w};
    }
  }
#pragma unroll 1
  for (int j = 0; j < 4; ++j) {
    const int l = l0 + j;
    float4 w4[16];
    const float4* wp = (const float4*)(wn + (((size_t)l * G_ + g) * B_ + b) * SD);
#pragma unroll
    for (int q = 0; q < 16; ++q) w4[q] = wp[q];
    float4 u4[4];
    const float4* up = (const float4*)(inp + (((size_t)g * B_ + b) * L_ + l) * ID);
#pragma unroll
    for (int q = 0; q < 4; ++q) u4[q] = up[q];
    float4 v4[4];
    const float4* vp = (const float4*)(vn + (((size_t)l * G_ + g) * B_ + b) * OD);
#pragma unroll
    for (int q = 0; q < 4; ++q) v4[q] = vp[q];

    __syncthreads();  // A: prev-step zb/ob readers drained (no-op at j==0)
#pragma unroll 1
    for (int c = 0; c < 16; ++c) {
      const int row = row0 + c;  // uniform
      const float4* fr = (const float4*)(Fg + row * SD);
      const float4* sr = (const float4*)(Wg + row * SD);
      const float4* br = (const float4*)(Bg + row * ID);
      v2 a0 = {0.f, 0.f}, a1 = {0.f, 0.f}, a2 = {0.f, 0.f}, a3 = {0.f, 0.f};
#pragma unroll
      for (int q = 0; q < 16; ++q) {
        float4 f = fr[q];   // uniform -> s_load
        float4 s = sr[q];   // uniform -> s_load
        float4 w = w4[q];
        a0 += (v2){f.x, f.y} * z2[2 * q];
        a1 += (v2){f.z, f.w} * z2[2 * q + 1];
        a2 += (v2){s.x, s.y} * (v2){w.x, w.y};
        a3 += (v2){s.z, s.w} * (v2){w.z, w.w};
      }
#pragma unroll
      for (int q = 0; q < 4; ++q) {
        float4 bb = br[q];  // uniform -> s_load
        float4 u = u4[q];
        a2 += (v2){bb.x, bb.y} * (v2){u.x, u.y};
        a3 += (v2){bb.z, bb.w} * (v2){u.z, u.w};
      }
      v2 aa = (a0 + a1) + (a2 + a3);
      zb[row * 64 + lane] = aa.x + aa.y;
    }
    __syncthreads();  // B: zb = state(l) complete
    // cooperative state store
    {
      float* dst = out + slotof(g, half * 64 + item, l);
#pragma unroll
      for (int r = 0; r < 4; ++r) {
        float4 v;
        v.x = zb[(kg * 16 + 4 * r + 0) * 64 + item];
        v.y = zb[(kg * 16 + 4 * r + 1) * 64 + item];
        v.z = zb[(kg * 16 + 4 * r + 2) * 64 + item];
        v.w = zb[(kg * 16 + 4 * r + 3) * 64 + item];
        ((float4*)dst)[kg * 4 + r] = v;
      }
    }
    // regather full state(l) into regs (also feeds next step)
#pragma unroll
    for (int k = 0; k < 32; ++k)
      z2[k] = (v2){zb[(2 * k) * 64 + lane], zb[(2 * k + 1) * 64 + lane]};
    // observations: wave ww computes obs rows [4ww, 4ww+4)
#pragma unroll
    for (int oc = 0; oc < 4; ++oc) {
      const int orow = ww * 4 + oc;  // uniform
      const float4* hr = (const float4*)(Hg + orow * SD);
      const float4* vr = (const float4*)(Vg + orow * OD);
      v2 a0 = {0.f, 0.f}, a1 = {0.f, 0.f};
#pragma unroll
      for (int q = 0; q < 16; ++q) {
        float4 h = hr[q];   // uniform -> s_load
        a0 += (v2){h.x, h.y} * z2[2 * q];
        a1 += (v2){h.z, h.w} * z2[2 * q + 1];
      }
#pragma unroll
      for (int q = 0; q < 4; ++q) {
        float4 sv = vr[q];  // uniform -> s_load
        float4 vv = v4[q];
        a0 += (v2){sv.x, sv.y} * (v2){vv.x, vv.y};
        a1 += (v2){sv.z, sv.w} * (v2){vv.z, vv.w};
      }
      v2 aa = a0 + a1;
      ob[orow * 64 + lane] = aa.x + aa.y;
    }
    __syncthreads();  // C: ob complete
    // cooperative obs store: thread (item, kg) stores float4 #kg
    {
      float4 v;
      v.x = ob[(4 * kg + 0) * 64 + item];
      v.y = ob[(4 * kg + 1) * 64 + item];
      v.z = ob[(4 * kg + 2) * 64 + item];
      v.w = ob[(4 * kg + 3) * 64 + item];
      float* od = out + OBS_BASE +
                  (((size_t)g * B_ + (half * 64 + item)) * L_ + l) * OD;
      ((float4*)od)[kg] = v;
    }
  }
}

extern "C" void kernel_launch(void* const* d_in, const int* in_sizes, int n_in,
                              void* d_out, int out_size, void* d_ws, size_t ws_size,
                              hipStream_t stream) {
  (void)in_sizes; (void)n_in; (void)out_size; (void)d_ws; (void)ws_size;
  const float* state0 = (const float*)d_in[0];
  const float* inputs = (const float*)d_in[1];
  const float* Fm     = (const float*)d_in[2];
  const float* Bm     = (const float*)d_in[3];
  const float* Hm     = (const float*)d_in[4];
  const float* SW     = (const float*)d_in[5];
  const float* SV     = (const float*)d_in[6];
  const float* wn     = (const float*)d_in[7];
  const float* vn     = (const float*)d_in[8];
  float* out = (float*)d_out;

  kA<<<2048, 256, 0, stream>>>(wn, inputs, Fm, Bm, SW, out);
  kB0<<<256, 256, 0, stream>>>(Fm, out);
  kB1<<<64, 256, 0, stream>>>(Fm, state0, out);
  kB2<<<256, 256, 0, stream>>>(Fm, out);
  kC<<<2048, 256, 0, stream>>>(wn, inputs, vn, Fm, Bm, Hm, SW, SV, out);
}